// Round 1
// baseline (109.877 us; speedup 1.0000x reference)
//
#include <hip/hip_runtime.h>
#include <math.h>

// LIF forward scan: v = v*decay*(1-z_prev) + x_t ; z = (v > 0.5)
// B=256, T=1000, H=256. One thread per (b,h) chain; lane index = h so each
// timestep's wave access is 64 consecutive floats (fully coalesced).
constexpr int T_LEN  = 1000;
constexpr int H_DIM  = 256;
constexpr int KB     = 20;            // timesteps per register batch; 1000 % 20 == 0
constexpr int NBATCH = T_LEN / KB;    // 50 (even -> clean double buffering)

__global__ __launch_bounds__(256)
void lif_fwd(const float* __restrict__ x,
             const float* __restrict__ decay_logit,
             float* __restrict__ out)
{
#pragma clang fp contract(off)   // must NOT fuse mul+add: match numpy rounding
    const int h = threadIdx.x;       // 0..255  (H_DIM == blockDim.x)
    const int b = blockIdx.x;        // 0..255  (one block per batch row)
    const size_t base = (size_t)b * (size_t)(T_LEN * H_DIM) + (size_t)h;
    const float* __restrict__ xp = x + base;
    float* __restrict__       op = out + base;

    // decay = sigmoid(decay_logit[h]); compute in double, round once to f32.
    const float  dlog = decay_logit[h];
    const float  dcy  = (float)(1.0 / (1.0 + exp(-(double)dlog)));

    float v = 0.0f;
    bool  z = false;

    float bufA[KB], bufB[KB];

    // prime pipeline: batch 0
#pragma unroll
    for (int k = 0; k < KB; ++k)
        bufA[k] = xp[(size_t)k * H_DIM];

    for (int i = 0; i < NBATCH; i += 2) {
        // prefetch batch i+1 (always exists: NBATCH is even)
#pragma unroll
        for (int k = 0; k < KB; ++k)
            bufB[k] = xp[((size_t)(i + 1) * KB + k) * H_DIM];

        // compute batch i from bufA
#pragma unroll
        for (int k = 0; k < KB; ++k) {
            float vd = v * dcy;            // round(v*d)
            float vg = z ? 0.0f : vd;      // *(1-z): exact (x0 or x1)
            v = vg + bufA[k];              // round(+x_t)
            z = (v > 0.5f);                // == (v - 0.5 > 0), exact sign
            op[((size_t)i * KB + k) * H_DIM] = z ? 1.0f : 0.0f;
        }

        // prefetch batch i+2
        if (i + 2 < NBATCH) {
#pragma unroll
            for (int k = 0; k < KB; ++k)
                bufA[k] = xp[((size_t)(i + 2) * KB + k) * H_DIM];
        }

        // compute batch i+1 from bufB
#pragma unroll
        for (int k = 0; k < KB; ++k) {
            float vd = v * dcy;
            float vg = z ? 0.0f : vd;
            v = vg + bufB[k];
            z = (v > 0.5f);
            op[((size_t)(i + 1) * KB + k) * H_DIM] = z ? 1.0f : 0.0f;
        }
    }
}

extern "C" void kernel_launch(void* const* d_in, const int* in_sizes, int n_in,
                              void* d_out, int out_size, void* d_ws, size_t ws_size,
                              hipStream_t stream)
{
    const float* x  = (const float*)d_in[0];         // [B,T,H] f32
    const float* dl = (const float*)d_in[1];         // [H] f32
    float*       o  = (float*)d_out;                 // [B,T,H] f32 spikes

    const int B = in_sizes[0] / (T_LEN * H_DIM);     // 256
    lif_fwd<<<B, H_DIM, 0, stream>>>(x, dl, o);
}

// Round 3
// 104.335 us; speedup vs baseline: 1.0531x; 1.0531x over previous
//
#include <hip/hip_runtime.h>
#include <math.h>

// LIF forward scan: v = v*decay*(1-z_prev) + x_t ; z = (v > 0.5)
// B=256, T=1000, H=256. One thread per TWO adjacent (b,h) chains (h=2j,2j+1):
// 8B/lane nontemporal loads/stores, 20-deep double-buffered prefetch.
constexpr int T_LEN  = 1000;
constexpr int H_DIM  = 256;
constexpr int KB     = 20;            // timesteps per register batch; 1000 % 20 == 0
constexpr int NBATCH = T_LEN / KB;    // 50 (even -> clean double buffering)
constexpr int H2     = H_DIM / 2;     // vec2 elements per timestep row

typedef float v2f __attribute__((ext_vector_type(2)));  // native vector: OK for nontemporal builtins

__global__ __launch_bounds__(128)
void lif_fwd(const float* __restrict__ x,
             const float* __restrict__ decay_logit,
             float* __restrict__ out)
{
#pragma clang fp contract(off)   // must NOT fuse mul+add: match numpy rounding
    const int j = threadIdx.x;       // 0..127: chains h=2j and h=2j+1
    const int b = blockIdx.x;        // 0..255: one block per batch row
    const size_t base = (size_t)b * (size_t)(T_LEN * H_DIM) + (size_t)(2 * j);
    const v2f* __restrict__ xp = (const v2f*)(x + base);
    v2f* __restrict__       op = (v2f*)(out + base);

    // decay = sigmoid(decay_logit[h]); compute in double, round once to f32.
    const float dl0 = decay_logit[2 * j];
    const float dl1 = decay_logit[2 * j + 1];
    const float d0  = (float)(1.0 / (1.0 + exp(-(double)dl0)));
    const float d1  = (float)(1.0 / (1.0 + exp(-(double)dl1)));

    float v0 = 0.0f, v1 = 0.0f;
    bool  z0 = false, z1 = false;

    v2f bufA[KB], bufB[KB];

    // prime pipeline: batch 0
#pragma unroll
    for (int k = 0; k < KB; ++k)
        bufA[k] = __builtin_nontemporal_load(xp + (size_t)k * H2);

#pragma unroll 1
    for (int i = 0; i < NBATCH; i += 2) {
        // prefetch batch i+1 (always exists: NBATCH is even)
#pragma unroll
        for (int k = 0; k < KB; ++k)
            bufB[k] = __builtin_nontemporal_load(xp + ((size_t)(i + 1) * KB + k) * H2);

        // compute batch i from bufA
#pragma unroll
        for (int k = 0; k < KB; ++k) {
            float vd0 = v0 * d0;                 // round(v*d)
            float vd1 = v1 * d1;
            float vg0 = z0 ? 0.0f : vd0;         // *(1-z): exact (x0 or x1)
            float vg1 = z1 ? 0.0f : vd1;
            v0 = vg0 + bufA[k].x;                // round(+x_t)
            v1 = vg1 + bufA[k].y;
            z0 = (v0 > 0.5f);                    // == (v - 0.5 > 0)
            z1 = (v1 > 0.5f);
            v2f o;
            o.x = z0 ? 1.0f : 0.0f;
            o.y = z1 ? 1.0f : 0.0f;
            __builtin_nontemporal_store(o, op + ((size_t)i * KB + k) * H2);
        }

        // prefetch batch i+2
        if (i + 2 < NBATCH) {
#pragma unroll
            for (int k = 0; k < KB; ++k)
                bufA[k] = __builtin_nontemporal_load(xp + ((size_t)(i + 2) * KB + k) * H2);
        }

        // compute batch i+1 from bufB
#pragma unroll
        for (int k = 0; k < KB; ++k) {
            float vd0 = v0 * d0;
            float vd1 = v1 * d1;
            float vg0 = z0 ? 0.0f : vd0;
            float vg1 = z1 ? 0.0f : vd1;
            v0 = vg0 + bufB[k].x;
            v1 = vg1 + bufB[k].y;
            z0 = (v0 > 0.5f);
            z1 = (v1 > 0.5f);
            v2f o;
            o.x = z0 ? 1.0f : 0.0f;
            o.y = z1 ? 1.0f : 0.0f;
            __builtin_nontemporal_store(o, op + ((size_t)(i + 1) * KB + k) * H2);
        }
    }
}

extern "C" void kernel_launch(void* const* d_in, const int* in_sizes, int n_in,
                              void* d_out, int out_size, void* d_ws, size_t ws_size,
                              hipStream_t stream)
{
    const float* x  = (const float*)d_in[0];         // [B,T,H] f32
    const float* dl = (const float*)d_in[1];         // [H] f32
    float*       o  = (float*)d_out;                 // [B,T,H] f32 spikes

    const int B = in_sizes[0] / (T_LEN * H_DIM);     // 256
    lif_fwd<<<B, H2, 0, stream>>>(x, dl, o);
}

// Round 4
// 104.225 us; speedup vs baseline: 1.0542x; 1.0011x over previous
//
#include <hip/hip_runtime.h>
#include <math.h>

// LIF forward scan: v = v*decay*(1-z_prev) + x_t ; z = (v > 0.5)
// B=256, T=1000, H=256. One wave (64 threads) per batch row; each thread owns
// FOUR adjacent chains (h=4l..4l+3): 16B/lane loads/stores (1KB per wave
// instruction, like the 6.3 TB/s copy ubench), 20-deep double-buffered
// prefetch (~20KB reads in flight per wave, <=60 VMEM ops outstanding).
constexpr int T_LEN  = 1000;
constexpr int H_DIM  = 256;
constexpr int KB     = 20;            // timesteps per register batch; 1000 % 20 == 0
constexpr int NBATCH = T_LEN / KB;    // 50 (even -> clean double buffering)
constexpr int H4     = H_DIM / 4;     // vec4 elements per timestep row (=64)

typedef float v4f __attribute__((ext_vector_type(4)));

__global__ __launch_bounds__(64)
void lif_fwd(const float* __restrict__ x,
             const float* __restrict__ decay_logit,
             float* __restrict__ out)
{
#pragma clang fp contract(off)   // must NOT fuse mul+add: match numpy rounding
    const int l = threadIdx.x;       // 0..63: chains h=4l..4l+3
    const int b = blockIdx.x;        // 0..255: one block (one wave) per batch row
    const size_t base = (size_t)b * (size_t)(T_LEN * H_DIM) + (size_t)(4 * l);
    const v4f* __restrict__ xp = (const v4f*)(x + base);
    v4f* __restrict__       op = (v4f*)(out + base);

    // decay = sigmoid(decay_logit[h]); compute in double, round once to f32.
    float d[4], v[4];
    bool  z[4];
#pragma unroll
    for (int c = 0; c < 4; ++c) {
        d[c] = (float)(1.0 / (1.0 + exp(-(double)decay_logit[4 * l + c])));
        v[c] = 0.0f;
        z[c] = false;
    }

    v4f bufA[KB], bufB[KB];

    // prime pipeline: batch 0
#pragma unroll
    for (int k = 0; k < KB; ++k)
        bufA[k] = __builtin_nontemporal_load(xp + (size_t)k * H4);

#pragma unroll 1
    for (int i = 0; i < NBATCH; i += 2) {
        // prefetch batch i+1 (always exists: NBATCH is even)
#pragma unroll
        for (int k = 0; k < KB; ++k)
            bufB[k] = __builtin_nontemporal_load(xp + ((size_t)(i + 1) * KB + k) * H4);

        // compute batch i from bufA
#pragma unroll
        for (int k = 0; k < KB; ++k) {
            v4f xi = bufA[k], o;
#pragma unroll
            for (int c = 0; c < 4; ++c) {
                float vd = v[c] * d[c];          // round(v*d)
                float vg = z[c] ? 0.0f : vd;     // *(1-z): exact (x0 or x1)
                v[c] = vg + xi[c];               // round(+x_t)
                z[c] = (v[c] > 0.5f);            // == (v - 0.5 > 0)
                o[c] = z[c] ? 1.0f : 0.0f;
            }
            __builtin_nontemporal_store(o, op + ((size_t)i * KB + k) * H4);
        }

        // prefetch batch i+2
        if (i + 2 < NBATCH) {
#pragma unroll
            for (int k = 0; k < KB; ++k)
                bufA[k] = __builtin_nontemporal_load(xp + ((size_t)(i + 2) * KB + k) * H4);
        }

        // compute batch i+1 from bufB
#pragma unroll
        for (int k = 0; k < KB; ++k) {
            v4f xi = bufB[k], o;
#pragma unroll
            for (int c = 0; c < 4; ++c) {
                float vd = v[c] * d[c];
                float vg = z[c] ? 0.0f : vd;
                v[c] = vg + xi[c];
                z[c] = (v[c] > 0.5f);
                o[c] = z[c] ? 1.0f : 0.0f;
            }
            __builtin_nontemporal_store(o, op + ((size_t)(i + 1) * KB + k) * H4);
        }
    }
}

extern "C" void kernel_launch(void* const* d_in, const int* in_sizes, int n_in,
                              void* d_out, int out_size, void* d_ws, size_t ws_size,
                              hipStream_t stream)
{
    const float* x  = (const float*)d_in[0];         // [B,T,H] f32
    const float* dl = (const float*)d_in[1];         // [H] f32
    float*       o  = (float*)d_out;                 // [B,T,H] f32 spikes

    const int B = in_sizes[0] / (T_LEN * H_DIM);     // 256
    lif_fwd<<<B, 64, 0, stream>>>(x, dl, o);
}

// Round 5
// 94.778 us; speedup vs baseline: 1.1593x; 1.0997x over previous
//
#include <hip/hip_runtime.h>
#include <math.h>

// LIF forward scan: v = v*decay*(1-z_prev) + x_t ; z = (v > 0.5)
// B=256, T=1000, H=256. One block (256 thr = 4 waves) per batch row.
// x rows staged into a 3-slot LDS ring via global_load_lds (1KB/instr),
// depth-2 prefetch with counted vmcnt (never drained to 0 in the loop).
// Each thread owns chain h = tid; compute reads x from LDS, stores spikes.
constexpr int T_LEN  = 1000;
constexpr int H_DIM  = 256;
constexpr int BATCH  = 20;               // rows per batch (20 KB)
constexpr int NBATCH = T_LEN / BATCH;    // 50
constexpr int RING   = 3;                // LDS ring slots (60 KB)
constexpr int DEPTH  = 2;                // batches prefetched ahead
constexpr int RPW    = BATCH / 4;        // rows staged per wave = 5

typedef const __attribute__((address_space(1))) float g_f;
typedef __attribute__((address_space(3))) float l_f;

__global__ __launch_bounds__(256)
void lif_fwd(const float* __restrict__ x,
             const float* __restrict__ decay_logit,
             float* __restrict__ out)
{
#pragma clang fp contract(off)   // must NOT fuse mul+add: match numpy rounding
    __shared__ float X[RING][BATCH][H_DIM];   // 61440 B

    const int tid  = threadIdx.x;        // 0..255: chain h = tid
    const int wv   = tid >> 6;           // wave 0..3
    const int lane = tid & 63;
    const int b    = blockIdx.x;         // batch row

    const float* __restrict__ xrow = x   + (size_t)b * (T_LEN * H_DIM);
    float* __restrict__       orow = out + (size_t)b * (T_LEN * H_DIM) + tid;

    // decay = sigmoid(decay_logit[h]); double precision, rounded once to f32.
    const float d = (float)(1.0 / (1.0 + exp(-(double)decay_logit[tid])));
    float v = 0.0f;
    bool  z = false;

    // Stage batch `bt`: wave wv copies rows [wv*RPW, wv*RPW+RPW) into the ring.
    // Global src is per-lane (lane*16B); LDS dest is wave-uniform (HW adds lane*16).
    auto stage = [&](int bt) {
        const float* gsrc = xrow + (size_t)bt * (BATCH * H_DIM)
                                 + (size_t)(wv * RPW) * H_DIM + lane * 4;
        l_f* lds = (l_f*)&X[bt % RING][wv * RPW][0];
#pragma unroll
        for (int r = 0; r < RPW; ++r)
            __builtin_amdgcn_global_load_lds((g_f*)(gsrc + r * H_DIM),
                                             lds + r * H_DIM, 16, 0, 0);
    };

    stage(0);
    stage(1);

#pragma unroll 1
    for (int j = 0; j < NBATCH; ++j) {
        if (j + DEPTH < NBATCH) stage(j + DEPTH);   // 5 glds, stays in flight

        // Counted wait: guarantee batch j's rows landed, keep newer glds in flight.
        if (j == 0) { asm volatile("s_waitcnt vmcnt(10)" ::: "memory"); }
        else        { asm volatile("s_waitcnt vmcnt(30)" ::: "memory"); }
        __builtin_amdgcn_sched_barrier(0);
        __builtin_amdgcn_s_barrier();   // all waves' slices of batch j are in LDS

        const float(*Xj)[H_DIM] = X[j % RING];
        float* op = orow + (size_t)j * (BATCH * H_DIM);
#pragma unroll
        for (int t = 0; t < BATCH; ++t) {
            float xt = Xj[t][tid];           // LDS read, conflict-free
            float vd = v * d;                // round(v*d)
            float vg = z ? 0.0f : vd;        // *(1-z): exact
            v = vg + xt;                     // round(+x_t)
            z = (v > 0.5f);                  // == (v - 0.5 > 0)
            __builtin_nontemporal_store(z ? 1.0f : 0.0f, op + (size_t)t * H_DIM);
        }

        __builtin_amdgcn_s_barrier();   // close ring-slot reuse race (RING=3, DEPTH=2)
    }
}

extern "C" void kernel_launch(void* const* d_in, const int* in_sizes, int n_in,
                              void* d_out, int out_size, void* d_ws, size_t ws_size,
                              hipStream_t stream)
{
    const float* x  = (const float*)d_in[0];         // [B,T,H] f32
    const float* dl = (const float*)d_in[1];         // [H] f32
    float*       o  = (float*)d_out;                 // [B,T,H] f32 spikes

    const int B = in_sizes[0] / (T_LEN * H_DIM);     // 256
    lif_fwd<<<B, 256, 0, stream>>>(x, dl, o);
}

// Round 6
// 81.708 us; speedup vs baseline: 1.3448x; 1.1600x over previous
//
#include <hip/hip_runtime.h>
#include <math.h>

// LIF forward scan: v = v*decay*(1-z_prev) + x_t ; z = (v > 0.5)
// B=256, T=1000, H=256. One block (256 thr = 4 waves) per batch row.
// x rows staged into a 3-slot LDS ring via global_load_lds (1KB/instr),
// depth-2 prefetch with counted vmcnt (never drained to 0 in the loop).
// BATCH=40 rows/slot -> 80KB/CU of reads in flight (Little's law: the
// R1..R5 series shows BW tracks in-flight bytes at ~1.4us loaded latency).
constexpr int T_LEN  = 1000;
constexpr int H_DIM  = 256;
constexpr int BATCH  = 40;               // rows per batch (40 KB)
constexpr int NBATCH = T_LEN / BATCH;    // 25
constexpr int RING   = 3;                // LDS ring slots (120 KB)
constexpr int DEPTH  = 2;                // batches prefetched ahead
constexpr int RPW    = BATCH / 4;        // rows staged per wave = 10

typedef const __attribute__((address_space(1))) float g_f;
typedef __attribute__((address_space(3))) float l_f;

__global__ __launch_bounds__(256)
void lif_fwd(const float* __restrict__ x,
             const float* __restrict__ decay_logit,
             float* __restrict__ out)
{
#pragma clang fp contract(off)   // must NOT fuse mul+add: match numpy rounding
    __shared__ float X[RING][BATCH][H_DIM];   // 122880 B (gfx950 LDS = 160KB/CU)

    const int tid  = threadIdx.x;        // 0..255: chain h = tid
    const int wv   = tid >> 6;           // wave 0..3
    const int lane = tid & 63;
    const int b    = blockIdx.x;         // batch row

    const float* __restrict__ xrow = x   + (size_t)b * (T_LEN * H_DIM);
    float* __restrict__       orow = out + (size_t)b * (T_LEN * H_DIM) + tid;

    // decay = sigmoid(decay_logit[h]); double precision, rounded once to f32.
    const float d = (float)(1.0 / (1.0 + exp(-(double)decay_logit[tid])));
    float v = 0.0f;
    bool  z = false;

    // Stage batch `bt`: wave wv copies rows [wv*RPW, wv*RPW+RPW) into the ring.
    // Global src is per-lane (lane*16B); LDS dest is wave-uniform (HW adds lane*16).
    auto stage = [&](int bt) {
        const float* gsrc = xrow + (size_t)bt * (BATCH * H_DIM)
                                 + (size_t)(wv * RPW) * H_DIM + lane * 4;
        l_f* lds = (l_f*)&X[bt % RING][wv * RPW][0];
#pragma unroll
        for (int r = 0; r < RPW; ++r)
            __builtin_amdgcn_global_load_lds((g_f*)(gsrc + r * H_DIM),
                                             lds + r * H_DIM, 16, 0, 0);
    };

    stage(0);
    stage(1);

#pragma unroll 1
    for (int j = 0; j < NBATCH; ++j) {
        if (j + DEPTH < NBATCH) stage(j + DEPTH);   // 10 glds, stay in flight

        // Counted wait (in-order vmcnt): guarantee batch j's glds landed while
        // keeping newer glds + recent stores in flight.
        //   j=0: newer-than-glds(0) = glds(1,2) = 20
        //   j=1: newer-than-glds(1) = glds(2)+stores(0)+glds(3) = 60
        //   j>=2: newer-than-glds(j) = 100 -> any K<=100; 62 = minimal wait
        if      (j == 0) { asm volatile("s_waitcnt vmcnt(20)" ::: "memory"); }
        else if (j == 1) { asm volatile("s_waitcnt vmcnt(60)" ::: "memory"); }
        else             { asm volatile("s_waitcnt vmcnt(62)" ::: "memory"); }
        __builtin_amdgcn_sched_barrier(0);
        __builtin_amdgcn_s_barrier();   // all waves' slices of batch j are in LDS

        const float(*Xj)[H_DIM] = X[j % RING];
        float* op = orow + (size_t)j * (BATCH * H_DIM);
#pragma unroll
        for (int t = 0; t < BATCH; ++t) {
            float xt = Xj[t][tid];           // LDS read, conflict-free
            float vd = v * d;                // round(v*d)
            float vg = z ? 0.0f : vd;        // *(1-z): exact
            v = vg + xt;                     // round(+x_t)
            z = (v > 0.5f);                  // == (v - 0.5 > 0)
            __builtin_nontemporal_store(z ? 1.0f : 0.0f, op + (size_t)t * H_DIM);
        }

        __builtin_amdgcn_s_barrier();   // close ring-slot reuse race (RING=DEPTH+1)
    }
}

extern "C" void kernel_launch(void* const* d_in, const int* in_sizes, int n_in,
                              void* d_out, int out_size, void* d_ws, size_t ws_size,
                              hipStream_t stream)
{
    const float* x  = (const float*)d_in[0];         // [B,T,H] f32
    const float* dl = (const float*)d_in[1];         // [H] f32
    float*       o  = (float*)d_out;                 // [B,T,H] f32 spikes

    const int B = in_sizes[0] / (T_LEN * H_DIM);     // 256
    lif_fwd<<<B, 256, 0, stream>>>(x, dl, o);
}